// Round 1
// baseline (1457.729 us; speedup 1.0000x reference)
//
#include <hip/hip_runtime.h>

namespace {

constexpr int BATCH  = 32768;
constexpr int STEPS  = 20;
constexpr int WD     = 48;
constexpr float LR   = 0.1f;
constexpr float B1C  = 0.9f;
constexpr float B2C  = 0.999f;
constexpr float AEPS = 1e-8f;

// One wave (64 lanes) per sample. Lane j owns hidden unit j (j<48 active).
// 2nd-order forward-mode propagation: channels (value, d/dy, d2/dy2).
__global__ __launch_bounds__(64) void ebm_kernel(
    const float* __restrict__ x_in,  const float* __restrict__ eps_in,
    const float* __restrict__ W1,    const float* __restrict__ b1,
    const float* __restrict__ W2,    const float* __restrict__ b2,
    const float* __restrict__ W3,    const float* __restrict__ b3,
    const float* __restrict__ W4,
    float* __restrict__ out)
{
    const int s = blockIdx.x;        // sample
    const int j = threadIdx.x;       // hidden unit (0..63, 48 active)
    const bool act = (j < WD);

    // Per-lane weights (zeros for idle lanes -> their outputs are finite and
    // contribute 0 through W4).
    const float w1x = act ? W1[2*j]   : 0.f;
    const float w1y = act ? W1[2*j+1] : 0.f;
    const float bj1 = act ? b1[j] : 0.f;
    const float bj2 = act ? b2[j] : 0.f;
    const float bj3 = act ? b3[j] : 0.f;
    const float w4j = act ? W4[j] : 0.f;

    float w2r[WD], w3r[WD];
#pragma unroll
    for (int k = 0; k < WD; ++k) {
        w2r[k] = act ? W2[j*WD + k] : 0.f;
        w3r[k] = act ? W3[j*WD + k] : 0.f;
    }

    __shared__ float4 aS[64];   // (a, a', a'', pad) per unit

    const float xv = x_in[s];
    float y = 0.f, m = 0.f, v = 0.f;
    float pb1 = 1.f, pb2 = 1.f;

    for (int t = 0; t < STEPS; ++t) {
        const float e  = eps_in[t*BATCH + s];   // wave-uniform -> scalar load
        const float y0 = y + e;
        pb1 *= B1C; pb2 *= B2C;

        // ---- layer 1 (2 -> 48) ----
        float z  = fmaf(w1y, y0, fmaf(w1x, xv, bj1));
        float sg = 1.f / (1.f + __expf(-z));
        float sp = sg * (1.f - sg);
        float d1 = fmaf(z, sp, sg);                       // swish'
        float d2 = sp * fmaf(z, 1.f - 2.f*sg, 2.f);       // swish''
        float a   = z * sg;
        float ap  = d1 * w1y;                             // z' = w1y, z'' = 0
        float app = d2 * w1y * w1y;

        __syncthreads();                 // WAR guard vs prev-iter L3 reads
        aS[j] = make_float4(a, ap, app, 0.f);
        __syncthreads();

        // ---- layer 2 (48 -> 48) ----
        float z2 = bj2, z2p = 0.f, z2q = 0.f;
#pragma unroll
        for (int k = 0; k < WD; ++k) {
            const float4 t4 = aS[k];     // broadcast read (conflict-free)
            z2  = fmaf(w2r[k], t4.x, z2);
            z2p = fmaf(w2r[k], t4.y, z2p);
            z2q = fmaf(w2r[k], t4.z, z2q);
        }
        sg = 1.f / (1.f + __expf(-z2));
        sp = sg * (1.f - sg);
        d1 = fmaf(z2, sp, sg);
        d2 = sp * fmaf(z2, 1.f - 2.f*sg, 2.f);
        a   = z2 * sg;
        ap  = d1 * z2p;
        app = fmaf(d2 * z2p, z2p, d1 * z2q);

        __syncthreads();
        aS[j] = make_float4(a, ap, app, 0.f);
        __syncthreads();

        // ---- layer 3 (48 -> 48) ----
        float z3 = bj3, z3p = 0.f, z3q = 0.f;
#pragma unroll
        for (int k = 0; k < WD; ++k) {
            const float4 t4 = aS[k];
            z3  = fmaf(w3r[k], t4.x, z3);
            z3p = fmaf(w3r[k], t4.y, z3p);
            z3q = fmaf(w3r[k], t4.z, z3q);
        }
        sg = 1.f / (1.f + __expf(-z3));
        sp = sg * (1.f - sg);
        d1 = fmaf(z3, sp, sg);
        d2 = sp * fmaf(z3, 1.f - 2.f*sg, 2.f);
        ap  = d1 * z3p;
        app = fmaf(d2 * z3p, z3p, d1 * z3q);

        // ---- layer 4 (48 -> 1), derivatives only ----
        float pd1 = w4j * ap;    // E'(y0) partial
        float pd2 = w4j * app;   // E''(y0) partial
        for (int off = 32; off; off >>= 1) {
            pd1 += __shfl_xor(pd1, off);
            pd2 += __shfl_xor(pd2, off);
        }

        // g = E'(y0) + E''(y0)*(y - y0) = E'(y0) - E''(y0)*e
        const float g = fmaf(pd2, -e, pd1);

        // Adam
        m = fmaf(B1C, m, (1.f - B1C) * g);
        v = fmaf(B2C, v, (1.f - B2C) * g * g);
        const float mh = m / (1.f - pb1);
        const float vh = v / (1.f - pb2);
        y -= LR * mh / (sqrtf(vh) + AEPS);
    }

    if (j == 0) out[s] = y;
}

} // namespace

extern "C" void kernel_launch(void* const* d_in, const int* in_sizes, int n_in,
                              void* d_out, int out_size, void* d_ws, size_t ws_size,
                              hipStream_t stream) {
    const float* x   = (const float*)d_in[0];
    const float* eps = (const float*)d_in[1];
    const float* W1  = (const float*)d_in[2];
    const float* b1  = (const float*)d_in[3];
    const float* W2  = (const float*)d_in[4];
    const float* b2  = (const float*)d_in[5];
    const float* W3  = (const float*)d_in[6];
    const float* b3  = (const float*)d_in[7];
    const float* W4  = (const float*)d_in[8];
    float* out = (float*)d_out;

    ebm_kernel<<<BATCH, 64, 0, stream>>>(x, eps, W1, b1, W2, b2, W3, b3, W4, out);
}

// Round 2
// 868.205 us; speedup vs baseline: 1.6790x; 1.6790x over previous
//
#include <hip/hip_runtime.h>

namespace {

constexpr int BATCH  = 32768;
constexpr int STEPS  = 20;
constexpr int WD     = 48;
constexpr float LR   = 0.1f;
constexpr float B1C  = 0.9f;
constexpr float B2C  = 0.999f;
constexpr float AEPS = 1e-8f;

// Broadcast lane `lane`'s value of v to all lanes via v_readlane (SGPR result).
__device__ __forceinline__ float rl(float v, int lane) {
    return __int_as_float(__builtin_amdgcn_readlane(__float_as_int(v), lane));
}

// One wave per sample. Lane j owns hidden unit j (j<48 active).
// 2nd-order forward-mode propagation (value, d/dy, d2/dy2), no LDS:
// activations are broadcast lane->all via v_readlane into SGPRs.
__global__ __launch_bounds__(64) void ebm_kernel(
    const float* __restrict__ x_in,  const float* __restrict__ eps_in,
    const float* __restrict__ W1,    const float* __restrict__ b1,
    const float* __restrict__ W2,    const float* __restrict__ b2,
    const float* __restrict__ W3,    const float* __restrict__ b3,
    const float* __restrict__ W4,
    float* __restrict__ out)
{
    const int s = blockIdx.x;        // sample
    const int j = threadIdx.x;       // hidden unit (0..63, 48 active)
    const bool act = (j < WD);

    const float w1x = act ? W1[2*j]   : 0.f;
    const float w1y = act ? W1[2*j+1] : 0.f;
    const float bj1 = act ? b1[j] : 0.f;
    const float bj2 = act ? b2[j] : 0.f;
    const float bj3 = act ? b3[j] : 0.f;
    const float w4j = act ? W4[j] : 0.f;

    float w2r[WD], w3r[WD];
#pragma unroll
    for (int k = 0; k < WD; ++k) {
        w2r[k] = act ? W2[j*WD + k] : 0.f;
        w3r[k] = act ? W3[j*WD + k] : 0.f;
    }

    const float xv = x_in[s];
    float y = 0.f, m = 0.f, v = 0.f;
    float pb1 = 1.f, pb2 = 1.f;

    for (int t = 0; t < STEPS; ++t) {
        const float e  = eps_in[t*BATCH + s];
        const float y0 = y + e;
        pb1 *= B1C; pb2 *= B2C;

        // ---- layer 1 (2 -> 48) ----
        float z  = fmaf(w1y, y0, fmaf(w1x, xv, bj1));
        float sg = 1.f / (1.f + __expf(-z));
        float sp = sg * (1.f - sg);
        float d1 = fmaf(z, sp, sg);                       // swish'
        float d2 = sp * fmaf(z, 1.f - 2.f*sg, 2.f);       // swish''
        float a   = z * sg;
        float ap  = d1 * w1y;                             // z' = w1y, z'' = 0
        float app = d2 * w1y * w1y;

        // ---- layer 2 (48 -> 48), readlane broadcast ----
        float z2 = bj2, z2p = 0.f, z2q = 0.f;
#pragma unroll
        for (int k = 0; k < WD; ++k) {
            z2  = fmaf(w2r[k], rl(a,   k), z2);
            z2p = fmaf(w2r[k], rl(ap,  k), z2p);
            z2q = fmaf(w2r[k], rl(app, k), z2q);
        }
        sg = 1.f / (1.f + __expf(-z2));
        sp = sg * (1.f - sg);
        d1 = fmaf(z2, sp, sg);
        d2 = sp * fmaf(z2, 1.f - 2.f*sg, 2.f);
        a   = z2 * sg;
        ap  = d1 * z2p;
        app = fmaf(d2 * z2p, z2p, d1 * z2q);

        // ---- layer 3 (48 -> 48) ----
        float z3 = bj3, z3p = 0.f, z3q = 0.f;
#pragma unroll
        for (int k = 0; k < WD; ++k) {
            z3  = fmaf(w3r[k], rl(a,   k), z3);
            z3p = fmaf(w3r[k], rl(ap,  k), z3p);
            z3q = fmaf(w3r[k], rl(app, k), z3q);
        }
        sg = 1.f / (1.f + __expf(-z3));
        sp = sg * (1.f - sg);
        d1 = fmaf(z3, sp, sg);
        d2 = sp * fmaf(z3, 1.f - 2.f*sg, 2.f);
        ap  = d1 * z3p;
        app = fmaf(d2 * z3p, z3p, d1 * z3q);

        // ---- layer 4 (48 -> 1), derivatives only ----
        float pd1 = w4j * ap;    // E'(y0) partial
        float pd2 = w4j * app;   // E''(y0) partial
        for (int off = 32; off; off >>= 1) {
            pd1 += __shfl_xor(pd1, off);
            pd2 += __shfl_xor(pd2, off);
        }

        // g = E'(y0) + E''(y0)*(y - y0) = E'(y0) - E''(y0)*e
        const float g = fmaf(pd2, -e, pd1);

        // Adam
        m = fmaf(B1C, m, (1.f - B1C) * g);
        v = fmaf(B2C, v, (1.f - B2C) * g * g);
        const float mh = m / (1.f - pb1);
        const float vh = v / (1.f - pb2);
        y -= LR * mh / (sqrtf(vh) + AEPS);
    }

    if (j == 0) out[s] = y;
}

} // namespace

extern "C" void kernel_launch(void* const* d_in, const int* in_sizes, int n_in,
                              void* d_out, int out_size, void* d_ws, size_t ws_size,
                              hipStream_t stream) {
    const float* x   = (const float*)d_in[0];
    const float* eps = (const float*)d_in[1];
    const float* W1  = (const float*)d_in[2];
    const float* b1  = (const float*)d_in[3];
    const float* W2  = (const float*)d_in[4];
    const float* b2  = (const float*)d_in[5];
    const float* W3  = (const float*)d_in[6];
    const float* b3  = (const float*)d_in[7];
    const float* W4  = (const float*)d_in[8];
    float* out = (float*)d_out;

    ebm_kernel<<<BATCH, 64, 0, stream>>>(x, eps, W1, b1, W2, b2, W3, b3, W4, out);
}

// Round 3
// 437.675 us; speedup vs baseline: 3.3306x; 1.9837x over previous
//
#include <hip/hip_runtime.h>

namespace {

constexpr int BATCH = 32768;
constexpr int STEPS = 20;
constexpr int WD    = 48;
constexpr int WAVES = 4;           // waves per block
constexpr int IPW   = WD / WAVES;  // output units per wave
constexpr float LR   = 0.1f;
constexpr float B1C  = 0.9f;
constexpr float B2C  = 0.999f;
constexpr float AEPS = 1e-8f;

__device__ __forceinline__ void swish3(float z, float& a, float& d1, float& d2) {
    const float sg = 1.f / (1.f + __expf(-z));
    const float sp = sg * (1.f - sg);
    d1 = fmaf(z, sp, sg);                      // swish'
    d2 = sp * fmaf(z, 1.f - 2.f * sg, 2.f);    // swish''
    a  = z * sg;
}

// Sample-per-lane: lane = sample within the block's 64-sample group.
// 4 waves split the 48 hidden units (12 each); weights are wave-uniform ->
// scalar (s_load) operands. Activation triples round-trip through LDS.
__global__ __launch_bounds__(256, 2) void ebm_kernel(
    const float* __restrict__ x_in,  const float* __restrict__ eps_in,
    const float* __restrict__ W1,    const float* __restrict__ b1,
    const float* __restrict__ W2,    const float* __restrict__ b2,
    const float* __restrict__ W3,    const float* __restrict__ b3,
    const float* __restrict__ W4,
    float* __restrict__ out)
{
    const int lane = threadIdx.x & 63;
    const int wid  = __builtin_amdgcn_readfirstlane(threadIdx.x >> 6);
    const int s    = blockIdx.x * 64 + lane;

    __shared__ float4 actS[WD][64];        // (a, a', a'', pad) per unit per sample
    __shared__ float2 pdS[WAVES][64];      // per-wave (E', E'') partials

    const float xv = x_in[s];

    float av[WD], apv[WD], aqv[WD];        // current-layer activations (registers)
    float y = 0.f, m = 0.f, v = 0.f;
    float pb1 = 1.f, pb2 = 1.f;

    for (int t = 0; t < STEPS; ++t) {
        const float e  = eps_in[t * BATCH + s];
        const float y0 = y + e;
        pb1 *= B1C; pb2 *= B2C;

        // ---- layer 1 (2 -> 48): this wave's 12 units ----
        for (int ii = 0; ii < IPW; ++ii) {
            const int i = wid * IPW + ii;
            const float w1x = W1[2 * i];
            const float w1y = W1[2 * i + 1];
            float z = fmaf(w1y, y0, fmaf(w1x, xv, b1[i]));
            float a, d1, d2; swish3(z, a, d1, d2);
            actS[i][lane] = make_float4(a, d1 * w1y, d2 * w1y * w1y, 0.f);
        }
        __syncthreads();
#pragma unroll
        for (int k = 0; k < WD; ++k) {
            const float4 t4 = actS[k][lane];
            av[k] = t4.x; apv[k] = t4.y; aqv[k] = t4.z;
        }
        __syncthreads();                   // readers done before L2 overwrites

        // ---- layer 2 (48 -> 48): 12 units, weights via SGPR ----
        for (int ii = 0; ii < IPW; ++ii) {
            const int i = wid * IPW + ii;
            const float* __restrict__ wr = &W2[i * WD];
            float z = b2[i], zp = 0.f, zq = 0.f;
#pragma unroll
            for (int k = 0; k < WD; ++k) {
                const float w = wr[k];
                z  = fmaf(w, av[k],  z);
                zp = fmaf(w, apv[k], zp);
                zq = fmaf(w, aqv[k], zq);
            }
            float a, d1, d2; swish3(z, a, d1, d2);
            actS[i][lane] = make_float4(a, d1 * zp, fmaf(d2 * zp, zp, d1 * zq), 0.f);
        }
        __syncthreads();
#pragma unroll
        for (int k = 0; k < WD; ++k) {
            const float4 t4 = actS[k][lane];
            av[k] = t4.x; apv[k] = t4.y; aqv[k] = t4.z;
        }
        __syncthreads();

        // ---- layer 3 (48 -> 48) + layer 4 partial dot products ----
        float pd1 = 0.f, pd2 = 0.f;
        for (int ii = 0; ii < IPW; ++ii) {
            const int i = wid * IPW + ii;
            const float* __restrict__ wr = &W3[i * WD];
            float z = b3[i], zp = 0.f, zq = 0.f;
#pragma unroll
            for (int k = 0; k < WD; ++k) {
                const float w = wr[k];
                z  = fmaf(w, av[k],  z);
                zp = fmaf(w, apv[k], zp);
                zq = fmaf(w, aqv[k], zq);
            }
            float a, d1, d2; swish3(z, a, d1, d2);
            const float w4 = W4[i];
            pd1 = fmaf(w4, d1 * zp, pd1);
            pd2 = fmaf(w4, fmaf(d2 * zp, zp, d1 * zq), pd2);
        }
        pdS[wid][lane] = make_float2(pd1, pd2);
        __syncthreads();

        float g1 = 0.f, g2 = 0.f;
#pragma unroll
        for (int w = 0; w < WAVES; ++w) {
            const float2 p = pdS[w][lane];
            g1 += p.x; g2 += p.y;
        }
        // g = E'(y0) + E''(y0)*(y - y0) = E' - e*E''
        const float g = fmaf(g2, -e, g1);

        // Adam (replicated identically in all 4 waves)
        m = fmaf(B1C, m, (1.f - B1C) * g);
        v = fmaf(B2C, v, (1.f - B2C) * g * g);
        const float mh = m / (1.f - pb1);
        const float vh = v / (1.f - pb2);
        y -= LR * mh / (sqrtf(vh) + AEPS);

        __syncthreads();                   // pdS WAR before next step
    }

    if (wid == 0) out[s] = y;
}

} // namespace

extern "C" void kernel_launch(void* const* d_in, const int* in_sizes, int n_in,
                              void* d_out, int out_size, void* d_ws, size_t ws_size,
                              hipStream_t stream) {
    const float* x   = (const float*)d_in[0];
    const float* eps = (const float*)d_in[1];
    const float* W1  = (const float*)d_in[2];
    const float* b1  = (const float*)d_in[3];
    const float* W2  = (const float*)d_in[4];
    const float* b2  = (const float*)d_in[5];
    const float* W3  = (const float*)d_in[6];
    const float* b3  = (const float*)d_in[7];
    const float* W4  = (const float*)d_in[8];
    float* out = (float*)d_out;

    ebm_kernel<<<BATCH / 64, 64 * WAVES, 0, stream>>>(x, eps, W1, b1, W2, b2, W3, b3, W4, out);
}